// Round 5
// baseline (566.881 us; speedup 1.0000x reference)
//
#include <hip/hip_runtime.h>
#include <hip/hip_bf16.h>
#include <math.h>

#define BB 256
#define TT 512
#define DIN 64
#define ZZ 32
#define HH 64

typedef __attribute__((ext_vector_type(4))) float f32x4;
typedef __attribute__((ext_vector_type(8))) __bf16 bf16x8;

__device__ __forceinline__ f32x4 mfma16(bf16x8 a, bf16x8 b, f32x4 c) {
  return __builtin_amdgcn_mfma_f32_16x16x32_bf16(a, b, c, 0, 0, 0);
}

// elu = min(v, e^v - 1): identical for v<=0; for v>0 exact (expm1 >= v),
// inf-safe. One less VALU op than cmp+cndmask.
__device__ __forceinline__ float elu1(float v) {
  return fminf(v, __expf(v) - 1.f);
}
__device__ __forceinline__ f32x4 elu4(f32x4 v) {
  f32x4 r;
  r.x = elu1(v.x); r.y = elu1(v.y); r.z = elu1(v.z); r.w = elu1(v.w);
  return r;
}

// pack two f32x4 (tile0 regs, tile1 regs) into a bf16x8 MFMA operand.
// Slot (q,e) holds k = 16*(e>>2) + 4q + (e&3) == neuron held by D tiles.
__device__ __forceinline__ bf16x8 pack2(f32x4 a, f32x4 b) {
  bf16x8 r;
  r[0] = (__bf16)a.x; r[1] = (__bf16)a.y; r[2] = (__bf16)a.z; r[3] = (__bf16)a.w;
  r[4] = (__bf16)b.x; r[5] = (__bf16)b.y; r[6] = (__bf16)b.z; r[7] = (__bf16)b.w;
  return r;
}

// hi/lo split pack: hi = RNE bf16, lo = bf16(v - float(hi)).
__device__ __forceinline__ void packhl(f32x4 a, f32x4 b, bf16x8& hi, bf16x8& lo) {
  hi = pack2(a, b);
  f32x4 ra, rb;
  ra.x = (float)hi[0]; ra.y = (float)hi[1]; ra.z = (float)hi[2]; ra.w = (float)hi[3];
  rb.x = (float)hi[4]; rb.y = (float)hi[5]; rb.z = (float)hi[6]; rb.w = (float)hi[7];
  lo = pack2(a - ra, b - rb);
}

__device__ __forceinline__ bf16x8 ldw(const float* rowp, int o1, int o2) {
  f32x4 a = *reinterpret_cast<const f32x4*>(rowp + o1);
  f32x4 b = *reinterpret_cast<const f32x4*>(rowp + o2);
  return pack2(a, b);
}
__device__ __forceinline__ void ldw2(const float* rowp, int o1, int o2,
                                     bf16x8& hi, bf16x8& lo) {
  f32x4 a = *reinterpret_cast<const f32x4*>(rowp + o1);
  f32x4 b = *reinterpret_cast<const f32x4*>(rowp + o2);
  packhl(a, b, hi, lo);
}

__device__ __forceinline__ float tanh1(float x) {
  float t = __expf(2.f * x);
  return 1.f - 2.f / (t + 1.f);
}
__device__ __forceinline__ f32x4 tanh4(f32x4 v) {
  f32x4 r;
  r.x = tanh1(v.x); r.y = tanh1(v.y); r.z = tanh1(v.z); r.w = tanh1(v.w);
  return r;
}

// ---------------------------------------------------------------------------
// RNN kernel: 16 batches/wave, operand-swapped MFMA, hi/lo bf16 recurrence.
// Layer-pipelined: iteration computes h0(t) and h1(t+1) in PARALLEL chains
// (layer 1 runs one step behind layer 0), halving the serial depth.
// hi/lo products tree'd (depth 2). x prefetched 5 steps ahead, 4 reg sets.
// ---------------------------------------------------------------------------
__global__ __launch_bounds__(64, 1) void rnn_kernel(
    const float* __restrict__ x,
    const float* __restrict__ Wi0, const float* __restrict__ Wh0,
    const float* __restrict__ bi0, const float* __restrict__ bh0,
    const float* __restrict__ Wi1, const float* __restrict__ Wh1,
    const float* __restrict__ bi1, const float* __restrict__ bh1,
    const float* __restrict__ h0g,
    float* __restrict__ rnn, float* __restrict__ out)
{
  const int lane = threadIdx.x & 63;
  const int q = lane >> 4, c = lane & 15;
  const int b0 = blockIdx.x * 16;
  const f32x4 Z4 = {0.f, 0.f, 0.f, 0.f};

  // ---- weight A-fragments (hi/lo) ----
  bf16x8 Wi0h[2][2], Wi0l[2][2];            // [kt][mt], 32x64
  #pragma unroll
  for (int kt = 0; kt < 2; ++kt)
    #pragma unroll
    for (int mt = 0; mt < 2; ++mt)
      ldw2(Wi0 + (16 * mt + c) * 64, 32 * kt + 4 * q, 32 * kt + 16 + 4 * q,
           Wi0h[kt][mt], Wi0l[kt][mt]);
  bf16x8 Wh0h[2], Wh0l[2], Wi1h[2], Wi1l[2], Wh1h[2], Wh1l[2];   // 32x32
  #pragma unroll
  for (int mt = 0; mt < 2; ++mt) {
    ldw2(Wh0 + (16 * mt + c) * 32, 4 * q, 16 + 4 * q, Wh0h[mt], Wh0l[mt]);
    ldw2(Wi1 + (16 * mt + c) * 32, 4 * q, 16 + 4 * q, Wi1h[mt], Wi1l[mt]);
    ldw2(Wh1 + (16 * mt + c) * 32, 4 * q, 16 + 4 * q, Wh1h[mt], Wh1l[mt]);
  }
  f32x4 B0b[2], B1b[2];
  #pragma unroll
  for (int mt = 0; mt < 2; ++mt) {
    B0b[mt] = *reinterpret_cast<const f32x4*>(bi0 + 16 * mt + 4 * q) +
              *reinterpret_cast<const f32x4*>(bh0 + 16 * mt + 4 * q);
    B1b[mt] = *reinterpret_cast<const f32x4*>(bi1 + 16 * mt + 4 * q) +
              *reinterpret_cast<const f32x4*>(bh1 + 16 * mt + 4 * q);
  }
  bf16x8 h0hi, h0lo, h1hi, h1lo;
  {
    f32x4 u0 = *reinterpret_cast<const f32x4*>(h0g + 4 * q);
    f32x4 u1 = *reinterpret_cast<const f32x4*>(h0g + 16 + 4 * q);
    packhl(u0, u1, h0hi, h0lo);
    u0 = *reinterpret_cast<const f32x4*>(h0g + 32 + 4 * q);
    u1 = *reinterpret_cast<const f32x4*>(h0g + 48 + 4 * q);
    packhl(u0, u1, h1hi, h1lo);
  }

  const float* px = x + (size_t)(b0 + c) * TT * DIN;
  float* pr = rnn + (size_t)(b0 + c) * TT * ZZ;
  float* po = out + (size_t)(b0 + c) * TT * ZZ;

  auto ldx = [&](int t, f32x4& r0, f32x4& r1, f32x4& r2, f32x4& r3) {
    const float* pt = px + (size_t)t * DIN;
    r0 = *reinterpret_cast<const f32x4*>(pt + 4 * q);
    r1 = *reinterpret_cast<const f32x4*>(pt + 16 + 4 * q);
    r2 = *reinterpret_cast<const f32x4*>(pt + 32 + 4 * q);
    r3 = *reinterpret_cast<const f32x4*>(pt + 48 + 4 * q);
  };
  auto p0chain = [&](bf16x8 xf0, bf16x8 xf1, int mt) -> f32x4 {
    return mfma16(Wi0l[1][mt], xf1, mfma16(Wi0h[1][mt], xf1,
           mfma16(Wi0l[0][mt], xf0, mfma16(Wi0h[0][mt], xf0, B0b[mt]))));
  };

  f32x4 P0c0, P0c1;

  // ---- peel: L0 at t=511 (layer 1 starts one iteration later) ----
  {
    f32x4 t0, t1, t2, t3;
    ldx(511, t0, t1, t2, t3);
    bf16x8 xf0 = pack2(t0, t1), xf1 = pack2(t2, t3);
    P0c0 = p0chain(xf0, xf1, 0);
    P0c1 = p0chain(xf0, xf1, 1);
    f32x4 A0 = mfma16(Wh0h[0], h0hi, P0c0);
    f32x4 A1 = mfma16(Wh0h[1], h0hi, P0c1);
    f32x4 L0l0 = mfma16(Wh0l[0], h0hi, mfma16(Wh0h[0], h0lo, Z4));
    f32x4 L0l1 = mfma16(Wh0l[1], h0hi, mfma16(Wh0h[1], h0lo, Z4));
    f32x4 d0 = tanh4(A0 + L0l0), d1 = tanh4(A1 + L0l1);
    packhl(d0, d1, h0hi, h0lo);
    // P0 for t=510
    ldx(510, t0, t1, t2, t3);
    xf0 = pack2(t0, t1); xf1 = pack2(t2, t3);
    P0c0 = p0chain(xf0, xf1, 0);
    P0c1 = p0chain(xf0, xf1, 1);
  }

  // ---- x prefetch pipeline: 4 sets, hold x(509..506) ----
  f32x4 Xa0, Xa1, Xa2, Xa3, Xb0, Xb1, Xb2, Xb3;
  f32x4 Xc0, Xc1, Xc2, Xc3, Xd0, Xd1, Xd2, Xd3;
  ldx(509, Xa0, Xa1, Xa2, Xa3);
  ldx(508, Xb0, Xb1, Xb2, Xb3);
  ldx(507, Xc0, Xc1, Xc2, Xc3);
  ldx(506, Xd0, Xd1, Xd2, Xd3);

  // SLOT(t): L0 at t, L1 at t+1 (parallel chains), P0 for t-1 from x regs,
  // reload x regs <- x(t-5).
  auto SLOT = [&](int t, f32x4& Xr0, f32x4& Xr1, f32x4& Xr2, f32x4& Xr3,
                  bool reload) {
    bf16x8 xf0 = pack2(Xr0, Xr1), xf1 = pack2(Xr2, Xr3);
    if (reload) {
      const int tl = t >= 5 ? t - 5 : 0;
      ldx(tl, Xr0, Xr1, Xr2, Xr3);
    }
    // ---- L0 trees (depth 2) ----
    f32x4 A0 = mfma16(Wh0h[0], h0hi, P0c0);
    f32x4 A1 = mfma16(Wh0h[1], h0hi, P0c1);
    f32x4 L0l0 = mfma16(Wh0l[0], h0hi, mfma16(Wh0h[0], h0lo, Z4));
    f32x4 L0l1 = mfma16(Wh0l[1], h0hi, mfma16(Wh0h[1], h0lo, Z4));
    // ---- L1 trees (depth 2), uses pre-update h0 (= h0(t+1)) ----
    f32x4 C10 = mfma16(Wi1h[0], h0hi, B1b[0]);
    f32x4 C11 = mfma16(Wi1h[1], h0hi, B1b[1]);
    f32x4 D10 = mfma16(Wi1l[0], h0hi, mfma16(Wi1h[0], h0lo, Z4));
    f32x4 D11 = mfma16(Wi1l[1], h0hi, mfma16(Wi1h[1], h0lo, Z4));
    f32x4 C20 = mfma16(Wh1h[0], h1hi, Z4);
    f32x4 C21 = mfma16(Wh1h[1], h1hi, Z4);
    f32x4 D20 = mfma16(Wh1l[0], h1hi, mfma16(Wh1h[0], h1lo, Z4));
    f32x4 D21 = mfma16(Wh1l[1], h1hi, mfma16(Wh1h[1], h1lo, Z4));
    // ---- P0 for next slot (off critical path) ----
    f32x4 p0 = p0chain(xf0, xf1, 0);
    f32x4 p1 = p0chain(xf0, xf1, 1);
    // ---- activations ----
    f32x4 d0 = tanh4(A0 + L0l0), d1 = tanh4(A1 + L0l1);
    f32x4 e0 = tanh4((C10 + C20) + (D10 + D20));
    f32x4 e1 = tanh4((C11 + C21) + (D11 + D21));
    // ---- store h1(t+1) ----
    const int t1 = t + 1;
    float* prt = pr + (size_t)t1 * ZZ;
    *reinterpret_cast<f32x4*>(prt + 4 * q) = e0;
    *reinterpret_cast<f32x4*>(prt + 16 + 4 * q) = e1;
    if (t1 == TT - 1) {
      float* pot = po + (size_t)t1 * ZZ;
      *reinterpret_cast<f32x4*>(pot + 4 * q) = e0;
      *reinterpret_cast<f32x4*>(pot + 16 + 4 * q) = e1;
    }
    // ---- state updates ----
    packhl(d0, d1, h0hi, h0lo);
    packhl(e0, e1, h1hi, h1lo);
    P0c0 = p0; P0c1 = p1;
  };

  #pragma unroll 1
  for (int g = 0; g < 127; ++g) {
    const int tb = 510 - 4 * g;
    SLOT(tb,     Xa0, Xa1, Xa2, Xa3, true);
    SLOT(tb - 1, Xb0, Xb1, Xb2, Xb3, true);
    SLOT(tb - 2, Xc0, Xc1, Xc2, Xc3, true);
    SLOT(tb - 3, Xd0, Xd1, Xd2, Xd3, true);
  }
  SLOT(2, Xa0, Xa1, Xa2, Xa3, false);
  SLOT(1, Xb0, Xb1, Xb2, Xb3, false);
  SLOT(0, Xc0, Xc1, Xc2, Xc3, false);
  // h1(0) is never consumed (out rows 0..510 come from the ODE) -> done.
}

// ---------------------------------------------------------------------------
// ODE kernel: R3 structure (verified) + elu-min tweak.
// ---------------------------------------------------------------------------
__global__ __launch_bounds__(256, 2) void ode_kernel(
    const float* __restrict__ rnn,
    const float* __restrict__ w1, const float* __restrict__ b1,
    const float* __restrict__ w2, const float* __restrict__ b2,
    const float* __restrict__ w3, const float* __restrict__ b3,
    float* __restrict__ out)
{
  const int lane = threadIdx.x & 63;
  const int wv = threadIdx.x >> 6;
  const int q = lane >> 4, c = lane & 15;

  bf16x8 W1[4], W2[2][4], W3[2][2];
  f32x4 BZ1[4], BZ2[4], BZ3[2];
  #pragma unroll
  for (int mt = 0; mt < 4; ++mt) {
    W1[mt] = ldw(w1 + (16 * mt + c) * 32, 4 * q, 16 + 4 * q);
    BZ1[mt] = *reinterpret_cast<const f32x4*>(b1 + 16 * mt + 4 * q);
    BZ2[mt] = *reinterpret_cast<const f32x4*>(b2 + 16 * mt + 4 * q);
  }
  #pragma unroll
  for (int kt = 0; kt < 2; ++kt)
    #pragma unroll
    for (int mt = 0; mt < 4; ++mt)
      W2[kt][mt] = ldw(w2 + (16 * mt + c) * 64, 32 * kt + 4 * q, 32 * kt + 16 + 4 * q);
  #pragma unroll
  for (int kt = 0; kt < 2; ++kt)
    #pragma unroll
    for (int mt = 0; mt < 2; ++mt)
      W3[kt][mt] = ldw(w3 + (16 * mt + c) * 64, 32 * kt + 4 * q, 32 * kt + 16 + 4 * q);
  #pragma unroll
  for (int mt = 0; mt < 2; ++mt)
    BZ3[mt] = *reinterpret_cast<const f32x4*>(b3 + 16 * mt + 4 * q);

  const unsigned row = 16u * (blockIdx.x * 4u + (unsigned)wv) + (unsigned)c;
  const unsigned bb = row / 511u, tp = row - bb * 511u;
  const float* srcp = rnn + ((size_t)bb * TT + tp + 1) * ZZ;
  f32x4 y0 = *reinterpret_cast<const f32x4*>(srcp + 4 * q);
  f32x4 y1 = *reinterpret_cast<const f32x4*>(srcp + 16 + 4 * q);

  f32x4 k0, k1, ks0, ks1;

  auto feval = [&](bf16x8 xf, f32x4& o0, f32x4& o1) {
    f32x4 a[4];
    #pragma unroll
    for (int mt = 0; mt < 4; ++mt) a[mt] = mfma16(W1[mt], xf, BZ1[mt]);
    #pragma unroll
    for (int mt = 0; mt < 4; ++mt) a[mt] = elu4(a[mt]);
    bf16x8 h10 = pack2(a[0], a[1]), h11 = pack2(a[2], a[3]);
    f32x4 g[4];
    #pragma unroll
    for (int mt = 0; mt < 4; ++mt)
      g[mt] = mfma16(W2[1][mt], h11, mfma16(W2[0][mt], h10, BZ2[mt]));
    #pragma unroll
    for (int mt = 0; mt < 4; ++mt) g[mt] = elu4(g[mt]);
    bf16x8 h20 = pack2(g[0], g[1]), h21 = pack2(g[2], g[3]);
    o0 = mfma16(W3[1][0], h21, mfma16(W3[0][0], h20, BZ3[0]));
    o1 = mfma16(W3[1][1], h21, mfma16(W3[0][1], h20, BZ3[1]));
  };

  const float hs = 0.01f;
  #pragma unroll 1
  for (int it = 0; it < 9; ++it) {
    feval(pack2(y0, y1), k0, k1);
    ks0 = k0; ks1 = k1;
    feval(pack2(y0 + (0.5f * hs) * k0, y1 + (0.5f * hs) * k1), k0, k1);
    ks0 += 2.f * k0; ks1 += 2.f * k1;
    feval(pack2(y0 + (0.5f * hs) * k0, y1 + (0.5f * hs) * k1), k0, k1);
    ks0 += 2.f * k0; ks1 += 2.f * k1;
    feval(pack2(y0 + hs * k0, y1 + hs * k1), k0, k1);
    y0 += (hs / 6.f) * (ks0 + k0);
    y1 += (hs / 6.f) * (ks1 + k1);
  }

  float* dstp = out + ((size_t)bb * TT + tp) * ZZ;
  *reinterpret_cast<f32x4*>(dstp + 4 * q) = y0;
  *reinterpret_cast<f32x4*>(dstp + 16 + 4 * q) = y1;
}

// ---------------------------------------------------------------------------
extern "C" void kernel_launch(void* const* d_in, const int* in_sizes, int n_in,
                              void* d_out, int out_size, void* d_ws, size_t ws_size,
                              hipStream_t stream) {
  const float* x   = (const float*)d_in[0];
  const float* Wi0 = (const float*)d_in[1];
  const float* Wh0 = (const float*)d_in[2];
  const float* bi0 = (const float*)d_in[3];
  const float* bh0 = (const float*)d_in[4];
  const float* Wi1 = (const float*)d_in[5];
  const float* Wh1 = (const float*)d_in[6];
  const float* bi1 = (const float*)d_in[7];
  const float* bh1 = (const float*)d_in[8];
  const float* h0  = (const float*)d_in[9];
  const float* w1  = (const float*)d_in[10];
  const float* b1  = (const float*)d_in[11];
  const float* w2  = (const float*)d_in[12];
  const float* b2  = (const float*)d_in[13];
  const float* w3  = (const float*)d_in[14];
  const float* b3  = (const float*)d_in[15];
  float* out = (float*)d_out;
  float* rnn = (float*)d_ws;   // B*T*Z fp32 = 16.7 MB scratch

  rnn_kernel<<<16, 64, 0, stream>>>(x, Wi0, Wh0, bi0, bh0,
                                    Wi1, Wh1, bi1, bh1, h0, rnn, out);
  ode_kernel<<<2044, 256, 0, stream>>>(rnn, w1, b1, w2, b2, w3, b3, out);
}

// Round 6
// 422.076 us; speedup vs baseline: 1.3431x; 1.3431x over previous
//
#include <hip/hip_runtime.h>
#include <hip/hip_bf16.h>
#include <math.h>

#define BB 256
#define TT 512
#define DIN 64
#define ZZ 32
#define HH 64

typedef __attribute__((ext_vector_type(4))) float f32x4;
typedef __attribute__((ext_vector_type(8))) __bf16 bf16x8;

__device__ __forceinline__ f32x4 mfma16(bf16x8 a, bf16x8 b, f32x4 c) {
  return __builtin_amdgcn_mfma_f32_16x16x32_bf16(a, b, c, 0, 0, 0);
}

// elu = min(v, e^v - 1): identical for v<=0, exact for v>0, inf-safe.
__device__ __forceinline__ float elu1(float v) {
  return fminf(v, __expf(v) - 1.f);
}
__device__ __forceinline__ f32x4 elu4(f32x4 v) {
  f32x4 r;
  r.x = elu1(v.x); r.y = elu1(v.y); r.z = elu1(v.z); r.w = elu1(v.w);
  return r;
}

// pack two f32x4 (tile0 regs, tile1 regs) into a bf16x8 MFMA operand.
// Slot (q,e) holds k = 16*(e>>2) + 4q + (e&3) == neuron held by D tiles.
__device__ __forceinline__ bf16x8 pack2(f32x4 a, f32x4 b) {
  bf16x8 r;
  r[0] = (__bf16)a.x; r[1] = (__bf16)a.y; r[2] = (__bf16)a.z; r[3] = (__bf16)a.w;
  r[4] = (__bf16)b.x; r[5] = (__bf16)b.y; r[6] = (__bf16)b.z; r[7] = (__bf16)b.w;
  return r;
}

// hi/lo split pack: hi = RNE bf16, lo = bf16(v - float(hi)).
__device__ __forceinline__ void packhl(f32x4 a, f32x4 b, bf16x8& hi, bf16x8& lo) {
  hi = pack2(a, b);
  f32x4 ra, rb;
  ra.x = (float)hi[0]; ra.y = (float)hi[1]; ra.z = (float)hi[2]; ra.w = (float)hi[3];
  rb.x = (float)hi[4]; rb.y = (float)hi[5]; rb.z = (float)hi[6]; rb.w = (float)hi[7];
  lo = pack2(a - ra, b - rb);
}

__device__ __forceinline__ bf16x8 ldw(const float* rowp, int o1, int o2) {
  f32x4 a = *reinterpret_cast<const f32x4*>(rowp + o1);
  f32x4 b = *reinterpret_cast<const f32x4*>(rowp + o2);
  return pack2(a, b);
}
__device__ __forceinline__ void ldw2(const float* rowp, int o1, int o2,
                                     bf16x8& hi, bf16x8& lo) {
  f32x4 a = *reinterpret_cast<const f32x4*>(rowp + o1);
  f32x4 b = *reinterpret_cast<const f32x4*>(rowp + o2);
  packhl(a, b, hi, lo);
}

// tanh via exp + raw v_rcp (rel err ~1ulp fp32 -- far below bf16 noise).
__device__ __forceinline__ float tanh1(float x) {
  float t = __expf(2.f * x);
  return fmaf(-2.f, __builtin_amdgcn_rcpf(t + 1.f), 1.f);
}
__device__ __forceinline__ f32x4 tanh4(f32x4 v) {
  f32x4 r;
  r.x = tanh1(v.x); r.y = tanh1(v.y); r.z = tanh1(v.z); r.w = tanh1(v.w);
  return r;
}

// ---------------------------------------------------------------------------
// prep_kernel: P0[b,t] = (bi0+bh0) + x[b,t] @ Wi0^T for all 131072 rows.
// Swapped-operand MFMA, hi/lo weights. Massively parallel, HBM-bound.
// Output (f32, [row][32]) goes to d_out used as scratch (fully overwritten
// later by rnn row 511 + ode rows 0..510).
// ---------------------------------------------------------------------------
__global__ __launch_bounds__(256, 2) void prep_kernel(
    const float* __restrict__ x,
    const float* __restrict__ Wi0,
    const float* __restrict__ bi0, const float* __restrict__ bh0,
    float* __restrict__ p0)
{
  const int lane = threadIdx.x & 63;
  const int wv = threadIdx.x >> 6;
  const int q = lane >> 4, c = lane & 15;

  bf16x8 Wh[2][2], Wl[2][2];   // [kt][mt]
  #pragma unroll
  for (int kt = 0; kt < 2; ++kt)
    #pragma unroll
    for (int mt = 0; mt < 2; ++mt)
      ldw2(Wi0 + (16 * mt + c) * 64, 32 * kt + 4 * q, 32 * kt + 16 + 4 * q,
           Wh[kt][mt], Wl[kt][mt]);
  f32x4 B0[2];
  #pragma unroll
  for (int mt = 0; mt < 2; ++mt)
    B0[mt] = *reinterpret_cast<const f32x4*>(bi0 + 16 * mt + 4 * q) +
             *reinterpret_cast<const f32x4*>(bh0 + 16 * mt + 4 * q);

  const unsigned row = blockIdx.x * 64u + (unsigned)wv * 16u + (unsigned)c;
  const float* xp = x + (size_t)row * DIN;
  f32x4 x0 = *reinterpret_cast<const f32x4*>(xp + 4 * q);
  f32x4 x1 = *reinterpret_cast<const f32x4*>(xp + 16 + 4 * q);
  f32x4 x2 = *reinterpret_cast<const f32x4*>(xp + 32 + 4 * q);
  f32x4 x3 = *reinterpret_cast<const f32x4*>(xp + 48 + 4 * q);
  bf16x8 xf0 = pack2(x0, x1), xf1 = pack2(x2, x3);

  float* pout = p0 + (size_t)row * ZZ;
  #pragma unroll
  for (int mt = 0; mt < 2; ++mt) {
    f32x4 a = mfma16(Wh[0][mt], xf0, B0[mt]);
    a = mfma16(Wl[0][mt], xf0, a);
    a = mfma16(Wh[1][mt], xf1, a);
    a = mfma16(Wl[1][mt], xf1, a);
    *reinterpret_cast<f32x4*>(pout + 16 * mt + 4 * q) = a;
  }
}

// ---------------------------------------------------------------------------
// rnn_kernel: fused 64-wide recurrence. z = [h0(t+1); h1(t+2)] ->
// [h0(t); h1(t+1)] = tanh(BIG*z + [P0(t); b1]), BIG = [[Wh0,0],[Wi1,Wh1]].
// 18 MFMAs in 10 independent depth<=2 chains per step; state hi/lo bf16;
// P0 prefetched 3 steps ahead (2 f32x4/step). 16 batches/wave, 16 waves.
// ---------------------------------------------------------------------------
__global__ __launch_bounds__(64, 1) void rnn_kernel(
    const float* __restrict__ p0buf,
    const float* __restrict__ Wh0,
    const float* __restrict__ Wi1, const float* __restrict__ Wh1,
    const float* __restrict__ bi1, const float* __restrict__ bh1,
    const float* __restrict__ h0g,
    float* __restrict__ rnn, float* __restrict__ out)
{
  const int lane = threadIdx.x & 63;
  const int q = lane >> 4, c = lane & 15;
  const int b0 = blockIdx.x * 16;
  const f32x4 Z4 = {0.f, 0.f, 0.f, 0.f};

  // ---- weight A-fragments (hi/lo) ----
  bf16x8 W0h[2], W0l[2];            // Wh0, K=32
  #pragma unroll
  for (int mt = 0; mt < 2; ++mt)
    ldw2(Wh0 + (16 * mt + c) * 32, 4 * q, 16 + 4 * q, W0h[mt], W0l[mt]);
  bf16x8 W1h[2][2], W1l[2][2];      // [kt][mt]; kt0 = Wi1, kt1 = Wh1
  #pragma unroll
  for (int mt = 0; mt < 2; ++mt) {
    ldw2(Wi1 + (16 * mt + c) * 32, 4 * q, 16 + 4 * q, W1h[0][mt], W1l[0][mt]);
    ldw2(Wh1 + (16 * mt + c) * 32, 4 * q, 16 + 4 * q, W1h[1][mt], W1l[1][mt]);
  }
  f32x4 B1[2];
  #pragma unroll
  for (int mt = 0; mt < 2; ++mt)
    B1[mt] = *reinterpret_cast<const f32x4*>(bi1 + 16 * mt + 4 * q) +
             *reinterpret_cast<const f32x4*>(bh1 + 16 * mt + 4 * q);

  // ---- initial state z = [h0_init; h1_init] ----
  bf16x8 zh0, zl0, zh1, zl1;
  {
    f32x4 u0 = *reinterpret_cast<const f32x4*>(h0g + 4 * q);
    f32x4 u1 = *reinterpret_cast<const f32x4*>(h0g + 16 + 4 * q);
    packhl(u0, u1, zh0, zl0);
    u0 = *reinterpret_cast<const f32x4*>(h0g + 32 + 4 * q);
    u1 = *reinterpret_cast<const f32x4*>(h0g + 48 + 4 * q);
    packhl(u0, u1, zh1, zl1);
  }

  const float* pp = p0buf + (size_t)(b0 + c) * TT * ZZ;
  float* pr = rnn + (size_t)(b0 + c) * TT * ZZ;
  float* po = out + (size_t)(b0 + c) * TT * ZZ;

  auto ldp = [&](int t, f32x4& m0, f32x4& m1) {
    const float* pt = pp + (size_t)t * ZZ;
    m0 = *reinterpret_cast<const f32x4*>(pt + 4 * q);
    m1 = *reinterpret_cast<const f32x4*>(pt + 16 + 4 * q);
  };

  // ---- peel t=511: compute h0(511) only; h1-part of z stays h1_init ----
  {
    f32x4 Pm0, Pm1;
    ldp(511, Pm0, Pm1);
    f32x4 dm0 = mfma16(W0h[0], zh0, Pm0);
    f32x4 dm1 = mfma16(W0h[1], zh0, Pm1);
    f32x4 dl0 = mfma16(W0l[0], zh0, mfma16(W0h[0], zl0, Z4));
    f32x4 dl1 = mfma16(W0l[1], zh0, mfma16(W0h[1], zl0, Z4));
    f32x4 d0 = tanh4(dm0 + dl0), d1 = tanh4(dm1 + dl1);
    packhl(d0, d1, zh0, zl0);
  }

  // ---- P0 prefetch: 3 rotating register pairs, distance 3 ----
  f32x4 Pa0, Pa1, Pb0, Pb1, Pc0, Pc1;
  ldp(510, Pa0, Pa1);
  ldp(509, Pb0, Pb1);
  ldp(508, Pc0, Pc1);

  auto SLOT = [&](int t, f32x4& Pm0, f32x4& Pm1, bool reload) {
    // h0-outputs (K=32): 3 MFMA x 2 tiles
    f32x4 dm0 = mfma16(W0h[0], zh0, Pm0);
    f32x4 dm1 = mfma16(W0h[1], zh0, Pm1);
    f32x4 dl0 = mfma16(W0l[0], zh0, mfma16(W0h[0], zl0, Z4));
    f32x4 dl1 = mfma16(W0l[1], zh0, mfma16(W0h[1], zl0, Z4));
    // h1-outputs (K=64): 6 MFMA x 2 tiles
    f32x4 ea0 = mfma16(W1h[1][0], zh1, mfma16(W1h[0][0], zh0, B1[0]));
    f32x4 ea1 = mfma16(W1h[1][1], zh1, mfma16(W1h[0][1], zh0, B1[1]));
    f32x4 eb0 = mfma16(W1h[1][0], zl1, mfma16(W1h[0][0], zl0, Z4));
    f32x4 eb1 = mfma16(W1h[1][1], zl1, mfma16(W1h[0][1], zl0, Z4));
    f32x4 ec0 = mfma16(W1l[1][0], zh1, mfma16(W1l[0][0], zh0, Z4));
    f32x4 ec1 = mfma16(W1l[1][1], zh1, mfma16(W1l[0][1], zh0, Z4));
    if (reload) {
      const int tl = t >= 3 ? t - 3 : 0;
      ldp(tl, Pm0, Pm1);
    }
    f32x4 d0 = tanh4(dm0 + dl0), d1 = tanh4(dm1 + dl1);
    f32x4 e0 = tanh4(ea0 + (eb0 + ec0)), e1 = tanh4(ea1 + (eb1 + ec1));
    // store h1(t+1)
    float* prt = pr + (size_t)(t + 1) * ZZ;
    *reinterpret_cast<f32x4*>(prt + 4 * q) = e0;
    *reinterpret_cast<f32x4*>(prt + 16 + 4 * q) = e1;
    if (t == 510) {   // h1(511) also goes to out row 511
      float* pot = po + (size_t)511 * ZZ;
      *reinterpret_cast<f32x4*>(pot + 4 * q) = e0;
      *reinterpret_cast<f32x4*>(pot + 16 + 4 * q) = e1;
    }
    packhl(d0, d1, zh0, zl0);
    packhl(e0, e1, zh1, zl1);
  };

  #pragma unroll 1
  for (int g = 0; g < 170; ++g) {
    const int tb = 510 - 3 * g;
    SLOT(tb,     Pa0, Pa1, true);
    SLOT(tb - 1, Pb0, Pb1, true);
    SLOT(tb - 2, Pc0, Pc1, true);
  }
  SLOT(0, Pa0, Pa1, false);   // produces h1(1); h0(0) discarded
}

// ---------------------------------------------------------------------------
// ODE kernel: unchanged from R5 (verified passing).
// ---------------------------------------------------------------------------
__global__ __launch_bounds__(256, 2) void ode_kernel(
    const float* __restrict__ rnn,
    const float* __restrict__ w1, const float* __restrict__ b1,
    const float* __restrict__ w2, const float* __restrict__ b2,
    const float* __restrict__ w3, const float* __restrict__ b3,
    float* __restrict__ out)
{
  const int lane = threadIdx.x & 63;
  const int wv = threadIdx.x >> 6;
  const int q = lane >> 4, c = lane & 15;

  bf16x8 W1[4], W2[2][4], W3[2][2];
  f32x4 BZ1[4], BZ2[4], BZ3[2];
  #pragma unroll
  for (int mt = 0; mt < 4; ++mt) {
    W1[mt] = ldw(w1 + (16 * mt + c) * 32, 4 * q, 16 + 4 * q);
    BZ1[mt] = *reinterpret_cast<const f32x4*>(b1 + 16 * mt + 4 * q);
    BZ2[mt] = *reinterpret_cast<const f32x4*>(b2 + 16 * mt + 4 * q);
  }
  #pragma unroll
  for (int kt = 0; kt < 2; ++kt)
    #pragma unroll
    for (int mt = 0; mt < 4; ++mt)
      W2[kt][mt] = ldw(w2 + (16 * mt + c) * 64, 32 * kt + 4 * q, 32 * kt + 16 + 4 * q);
  #pragma unroll
  for (int kt = 0; kt < 2; ++kt)
    #pragma unroll
    for (int mt = 0; mt < 2; ++mt)
      W3[kt][mt] = ldw(w3 + (16 * mt + c) * 64, 32 * kt + 4 * q, 32 * kt + 16 + 4 * q);
  #pragma unroll
  for (int mt = 0; mt < 2; ++mt)
    BZ3[mt] = *reinterpret_cast<const f32x4*>(b3 + 16 * mt + 4 * q);

  const unsigned row = 16u * (blockIdx.x * 4u + (unsigned)wv) + (unsigned)c;
  const unsigned bb = row / 511u, tp = row - bb * 511u;
  const float* srcp = rnn + ((size_t)bb * TT + tp + 1) * ZZ;
  f32x4 y0 = *reinterpret_cast<const f32x4*>(srcp + 4 * q);
  f32x4 y1 = *reinterpret_cast<const f32x4*>(srcp + 16 + 4 * q);

  f32x4 k0, k1, ks0, ks1;

  auto feval = [&](bf16x8 xf, f32x4& o0, f32x4& o1) {
    f32x4 a[4];
    #pragma unroll
    for (int mt = 0; mt < 4; ++mt) a[mt] = mfma16(W1[mt], xf, BZ1[mt]);
    #pragma unroll
    for (int mt = 0; mt < 4; ++mt) a[mt] = elu4(a[mt]);
    bf16x8 h10 = pack2(a[0], a[1]), h11 = pack2(a[2], a[3]);
    f32x4 g[4];
    #pragma unroll
    for (int mt = 0; mt < 4; ++mt)
      g[mt] = mfma16(W2[1][mt], h11, mfma16(W2[0][mt], h10, BZ2[mt]));
    #pragma unroll
    for (int mt = 0; mt < 4; ++mt) g[mt] = elu4(g[mt]);
    bf16x8 h20 = pack2(g[0], g[1]), h21 = pack2(g[2], g[3]);
    o0 = mfma16(W3[1][0], h21, mfma16(W3[0][0], h20, BZ3[0]));
    o1 = mfma16(W3[1][1], h21, mfma16(W3[0][1], h20, BZ3[1]));
  };

  const float hs = 0.01f;
  #pragma unroll 1
  for (int it = 0; it < 9; ++it) {
    feval(pack2(y0, y1), k0, k1);
    ks0 = k0; ks1 = k1;
    feval(pack2(y0 + (0.5f * hs) * k0, y1 + (0.5f * hs) * k1), k0, k1);
    ks0 += 2.f * k0; ks1 += 2.f * k1;
    feval(pack2(y0 + (0.5f * hs) * k0, y1 + (0.5f * hs) * k1), k0, k1);
    ks0 += 2.f * k0; ks1 += 2.f * k1;
    feval(pack2(y0 + hs * k0, y1 + hs * k1), k0, k1);
    y0 += (hs / 6.f) * (ks0 + k0);
    y1 += (hs / 6.f) * (ks1 + k1);
  }

  float* dstp = out + ((size_t)bb * TT + tp) * ZZ;
  *reinterpret_cast<f32x4*>(dstp + 4 * q) = y0;
  *reinterpret_cast<f32x4*>(dstp + 16 + 4 * q) = y1;
}

// ---------------------------------------------------------------------------
extern "C" void kernel_launch(void* const* d_in, const int* in_sizes, int n_in,
                              void* d_out, int out_size, void* d_ws, size_t ws_size,
                              hipStream_t stream) {
  const float* x   = (const float*)d_in[0];
  const float* Wi0 = (const float*)d_in[1];
  const float* Wh0 = (const float*)d_in[2];
  const float* bi0 = (const float*)d_in[3];
  const float* bh0 = (const float*)d_in[4];
  const float* Wi1 = (const float*)d_in[5];
  const float* Wh1 = (const float*)d_in[6];
  const float* bi1 = (const float*)d_in[7];
  const float* bh1 = (const float*)d_in[8];
  const float* h0  = (const float*)d_in[9];
  const float* w1  = (const float*)d_in[10];
  const float* b1  = (const float*)d_in[11];
  const float* w2  = (const float*)d_in[12];
  const float* b2  = (const float*)d_in[13];
  const float* w3  = (const float*)d_in[14];
  const float* b3  = (const float*)d_in[15];
  float* out = (float*)d_out;
  float* rnn = (float*)d_ws;      // B*T*Z fp32 = 16.7 MB scratch
  float* p0  = (float*)d_out;     // d_out doubles as P0 scratch; every byte
                                  // is overwritten later (ode rows 0..510,
                                  // rnn row 511) before validation.

  prep_kernel<<<2048, 256, 0, stream>>>(x, Wi0, bi0, bh0, p0);
  rnn_kernel<<<16, 64, 0, stream>>>(p0, Wh0, Wi1, Wh1, bi1, bh1, h0, rnn, out);
  ode_kernel<<<2044, 256, 0, stream>>>(rnn, w1, b1, w2, b2, w3, b3, out);
}